// Round 2
// baseline (221.502 us; speedup 1.0000x reference)
//
#include <hip/hip_runtime.h>

// Output layout (float32, flat):
//   [0 .. 25165824)  mask_a : (8, 12, 512, 512)
//   [25165824 .. )   mask_b : (8, 12, 512, 512)
// Channel groups (cc/3): 0=ones, 1=ABA checkerboard (i%2==j%2),
//                        2=row parity (i%2), 3=col parity (j%2).
// mask_b = 1 - mask_a for every group, so each thread computes the value
// pair once and stores both halves (two coalesced nontemporal float4 stores).

// Native clang vector type: __builtin_nontemporal_store rejects HIP's
// float4 class but accepts ext_vector_type.
typedef float f32x4 __attribute__((ext_vector_type(4)));

__global__ __launch_bounds__(256) void picmix_kernel(f32x4* __restrict__ out) {
    const unsigned int HALF4 = 6291456u;              // float4 elems per mask tensor
    const unsigned int stride = gridDim.x * blockDim.x;  // 2048*256 = 524288
    for (unsigned int idx4 = blockIdx.x * blockDim.x + threadIdx.x;
         idx4 < HALF4; idx4 += stride) {              // 12 iterations/thread, exact
        unsigned int id = idx4 * 4u;                  // flat float index in mask_a
        unsigned int cc = (id >> 18) % 12u;           // channel 0..11 (HW = 2^18)
        unsigned int g  = cc / 3u;                    // rule group 0..3 (wave-uniform)
        unsigned int ip = (id >> 9) & 1u;             // row parity (W = 512 = 2^9)
        // column parities within this float4 are (0,1,0,1): id%512 is a multiple of 4.

        float va0, va1;  // mask_a value at even/odd column
        if (g == 0u)      { va0 = 1.f;              va1 = 1.f; }
        else if (g == 1u) { va0 = ip ? 0.f : 1.f;   va1 = ip ? 1.f : 0.f; }
        else if (g == 2u) { va0 = (float)ip;        va1 = (float)ip; }
        else              { va0 = 0.f;              va1 = 1.f; }

        f32x4 a = {va0, va1, va0, va1};
        f32x4 b = {1.f - va0, 1.f - va1, 1.f - va0, 1.f - va1};
        __builtin_nontemporal_store(a, &out[idx4]);
        __builtin_nontemporal_store(b, &out[idx4 + HALF4]);
    }
}

extern "C" void kernel_launch(void* const* d_in, const int* in_sizes, int n_in,
                              void* d_out, int out_size, void* d_ws, size_t ws_size,
                              hipStream_t stream) {
    // Inputs img_a / img_b are unused: the reference's outputs are
    // deterministic parity masks independent of the image contents.
    (void)d_in; (void)in_sizes; (void)n_in; (void)d_ws; (void)ws_size; (void)out_size;
    // 2048 blocks = 8 workgroups/CU on 256 CUs; grid-stride covers the rest.
    picmix_kernel<<<2048, 256, 0, stream>>>((f32x4*)d_out);
}